// Round 1
// baseline (73.323 us; speedup 1.0000x reference)
//
#include <hip/hip_runtime.h>

// RankNet loss — but the reference only reads logs[:5, 0]:
//   output = sum_{i<5} log(1+exp(-dist(scores[i], scores[0]))) / 8192^2
// so only rows 0..4 of `data` are live. Total work ~34k FMAs -> single block.

__global__ void ranknet_head_kernel(const float* __restrict__ data,
                                    const float* __restrict__ W1,
                                    const float* __restrict__ b1,
                                    const float* __restrict__ W2,
                                    const float* __restrict__ b2,
                                    float* __restrict__ out) {
    constexpr int DIM  = 136;
    constexpr int H    = 50;
    constexpr int ROWS = 5;

    __shared__ float hW[ROWS][H];     // tanh(h) * W2[k], ready to row-sum
    __shared__ float scores[ROWS];

    const int t = threadIdx.x;

    // Phase 1: 250 threads each compute one (row, hidden-unit) dot product.
    if (t < ROWS * H) {
        const int r = t / H;
        const int k = t - r * H;
        float acc = b1[k];
        const float* __restrict__ dp = data + r * DIM;
        const float* __restrict__ wp = W1 + k * DIM;
        #pragma unroll 8
        for (int d = 0; d < DIM; ++d) {
            acc = fmaf(dp[d], wp[d], acc);
        }
        hW[r][k] = tanhf(acc) * W2[k];
    }
    __syncthreads();

    // Phase 2: 5 threads reduce hidden dim -> scores.
    if (t < ROWS) {
        float s = b2[0];
        #pragma unroll
        for (int k = 0; k < H; ++k) s += hW[t][k];
        scores[t] = s;
    }
    __syncthreads();

    // Phase 3: scalar epilogue on thread 0 (5 terms).
    if (t == 0) {
        const float y = scores[0];
        float total = 0.0f;
        for (int i = 0; i < ROWS; ++i) {
            const float x = scores[i];
            // replicate reference expression order exactly
            const float s = x * x * x - 3.0f * (x * x) * y
                          + 3.0f * x * (y * y) - y * y * y;
            const float sgn  = (s > 0.0f) ? 1.0f : ((s < 0.0f) ? -1.0f : 0.0f);
            const float dist = powf(fabsf(s + 1e-6f), 0.33f) * sgn;
            total += logf(1.0f + expf(-dist));
        }
        out[0] = total / 67108864.0f;  // 8192*8192 = 2^26 (exact in f32)
    }
}

extern "C" void kernel_launch(void* const* d_in, const int* in_sizes, int n_in,
                              void* d_out, int out_size, void* d_ws, size_t ws_size,
                              hipStream_t stream) {
    // setup_inputs order: data, ones, zeros, W1, b1, W2, b2
    const float* data = (const float*)d_in[0];
    // d_in[1] (ones) and d_in[2] (zeros) are dead in the reference.
    const float* W1 = (const float*)d_in[3];
    const float* b1 = (const float*)d_in[4];
    const float* W2 = (const float*)d_in[5];
    const float* b2 = (const float*)d_in[6];
    float* out = (float*)d_out;

    ranknet_head_kernel<<<1, 256, 0, stream>>>(data, W1, b1, W2, b2, out);
}

// Round 2
// 68.860 us; speedup vs baseline: 1.0648x; 1.0648x over previous
//
#include <hip/hip_runtime.h>

// RankNet loss — the reference only reads logs[:5, 0]:
//   output = sum_{i<5} log(1+exp(-dist(scores[i], scores[0]))) / 8192^2
// Only rows 0..4 of `data` are live; ones/zeros are dead. ~34k FMAs total.
//
// DIM = 136 floats = 34 float4 (rows are 544 B = 34*16 B aligned), so we
// vectorize the per-(row,hidden) dot product with float4 loads to shorten
// the dependent global-load latency chain (17 rounds -> ~5).

__global__ void ranknet_head_kernel(const float* __restrict__ data,
                                    const float* __restrict__ W1,
                                    const float* __restrict__ b1,
                                    const float* __restrict__ W2,
                                    const float* __restrict__ b2,
                                    float* __restrict__ out) {
    constexpr int DIM   = 136;
    constexpr int DIM4  = DIM / 4;   // 34
    constexpr int H     = 50;
    constexpr int ROWS  = 5;

    __shared__ float hW[ROWS][H];     // tanh(h) * W2[k]
    __shared__ float scores[ROWS];

    const int t = threadIdx.x;

    // Phase 1: 250 threads each compute one (row, hidden-unit) dot product.
    if (t < ROWS * H) {
        const int r = t / H;
        const int k = t - r * H;
        const float4* __restrict__ dp = (const float4*)(data + r * DIM);
        const float4* __restrict__ wp = (const float4*)(W1 + k * DIM);
        float a0 = 0.0f, a1 = 0.0f, a2 = 0.0f, a3 = 0.0f;
        #pragma unroll
        for (int d = 0; d < DIM4; ++d) {
            const float4 dv = dp[d];
            const float4 wv = wp[d];
            a0 = fmaf(dv.x, wv.x, a0);
            a1 = fmaf(dv.y, wv.y, a1);
            a2 = fmaf(dv.z, wv.z, a2);
            a3 = fmaf(dv.w, wv.w, a3);
        }
        const float acc = ((a0 + a1) + (a2 + a3)) + b1[k];
        hW[r][k] = tanhf(acc) * W2[k];
    }
    __syncthreads();

    // Phase 2: 5 threads reduce hidden dim -> scores.
    if (t < ROWS) {
        float s = b2[0];
        #pragma unroll
        for (int k = 0; k < H; ++k) s += hW[t][k];
        scores[t] = s;
    }
    __syncthreads();

    // Phase 3: scalar epilogue on thread 0 (5 terms).
    if (t == 0) {
        const float y = scores[0];
        float total = 0.0f;
        for (int i = 0; i < ROWS; ++i) {
            const float x = scores[i];
            // replicate reference expression order exactly
            const float s = x * x * x - 3.0f * (x * x) * y
                          + 3.0f * x * (y * y) - y * y * y;
            const float sgn  = (s > 0.0f) ? 1.0f : ((s < 0.0f) ? -1.0f : 0.0f);
            const float dist = powf(fabsf(s + 1e-6f), 0.33f) * sgn;
            total += logf(1.0f + expf(-dist));
        }
        out[0] = total / 67108864.0f;  // 8192*8192 = 2^26
    }
}

extern "C" void kernel_launch(void* const* d_in, const int* in_sizes, int n_in,
                              void* d_out, int out_size, void* d_ws, size_t ws_size,
                              hipStream_t stream) {
    // setup_inputs order: data, ones, zeros, W1, b1, W2, b2
    const float* data = (const float*)d_in[0];
    const float* W1 = (const float*)d_in[3];
    const float* b1 = (const float*)d_in[4];
    const float* W2 = (const float*)d_in[5];
    const float* b2 = (const float*)d_in[6];
    float* out = (float*)d_out;

    ranknet_head_kernel<<<1, 256, 0, stream>>>(data, W1, b1, W2, b2, out);
}